// Round 7
// baseline (190.826 us; speedup 1.0000x reference)
//
#include <hip/hip_runtime.h>
#include <math.h>

// Mamba2 chunked SSD forward (inclusive segsum), fp32 in/out, mixed split-f16 MFMA.
// b=2, s=4096, h=16, p=n=64, BL=64, chunks NC=64.
//
// Round-7: persistent 4-chunk blocks with cross-chunk register prefetch (T14).
//   k1p: 512 blocks x 256thr, 4 chunks each; LDS double-buffered (48.5 KB);
//        per-wave redundant A-scan (no dss LDS, no extra barrier); 1 barrier/chunk.
//   k2 : alias-free reg scan (unchanged structure; csw layout unified to trip-major)
//   k3p: 512 blocks x 256thr, 4 chunks each; LDS double-buffered (64.5 KB);
//        carry consumed from REGISTERS as MFMA B-operand (no G LDS buffer);
//        css from L2 via float4+scalars (no css LDS); exp factored, el[] reused.
// Rationale: r4 (instr count -44%) and r6 (waves/CU x2) were both NULL on k3 ->
// stall-convoy or L3-fabric-BW bound. This round overlaps chunk t+1 loads under
// chunk t compute to kill the stall component; if null again, ~4 TB/s L3 path
// is the confirmed ceiling.
//
// MFMA = v_mfma_f32_16x16x16_f16 (classic layout):
//   A: row=lane&15, k=4*(lane>>4)+i ; B: col=lane&15 ; D: row=4*(lane>>4)+r, col=lane&15
// LDS tiles: [64 rows][128B], XOR-swizzle byte^=((row&7)<<4) on write & read.

#define NB 2
#define SQ 4096
#define NH 16
#define NC 64

typedef _Float16 h4 __attribute__((ext_vector_type(4)));
typedef float f4 __attribute__((ext_vector_type(4)));

#define MFMA(a, b, c) __builtin_amdgcn_mfma_f32_16x16x16f16((a), (b), (c), 0, 0, 0)

__device__ __forceinline__ int swzb(int row, int byte_in_row) {
  return (row << 7) + (byte_in_row ^ ((row & 7) << 4));
}
__device__ __forceinline__ h4 ldh4(const _Float16* buf, int row, int chunk8) {
  return *reinterpret_cast<const h4*>(reinterpret_cast<const char*>(buf) +
                                      swzb(row, chunk8 << 3));
}
__device__ __forceinline__ void sth4(_Float16* buf, int row, int chunk8, h4 v) {
  *reinterpret_cast<h4*>(reinterpret_cast<char*>(buf) + swzb(row, chunk8 << 3)) = v;
}
__device__ __forceinline__ void sth1(_Float16* buf, int row, int col, _Float16 v) {
  *reinterpret_cast<_Float16*>(reinterpret_cast<char*>(buf) + swzb(row, col << 1)) = v;
}
__device__ __forceinline__ void cvt4(float x, float y, float z, float w, h4& hi, h4& lo) {
  hi.x = (_Float16)x; lo.x = (_Float16)(x - (float)hi.x);
  hi.y = (_Float16)y; lo.y = (_Float16)(y - (float)hi.y);
  hi.z = (_Float16)z; lo.z = (_Float16)(z - (float)hi.z);
  hi.w = (_Float16)w; lo.w = (_Float16)(w - (float)hi.w);
}
__device__ __forceinline__ h4 cvt4h(float x, float y, float z, float w) {
  h4 r; r.x = (_Float16)x; r.y = (_Float16)y; r.z = (_Float16)z; r.w = (_Float16)w;
  return r;
}

// ================================================================ kernel 1
struct K1R { float4 rx[4], rb[4]; float ra; };

__device__ __forceinline__ void k1_load(const float* X, const float* A,
    const float* Bm, int b, int h, int c, int tid, K1R& R) {
  const int l = tid & 63, cb2 = tid >> 6;
  const float* xs = X + (size_t)(b * SQ + c * 64 + l) * 1024 + h * 64 + cb2 * 16;
  const float* bs = Bm + (size_t)(b * SQ + c * 64 + l) * 1024 + h * 64 + cb2 * 16;
#pragma unroll
  for (int i = 0; i < 4; ++i) {
    R.rx[i] = ((const float4*)xs)[i];
    R.rb[i] = ((const float4*)bs)[i];
  }
  R.ra = A[(size_t)(b * SQ + c * 64 + l) * NH + h];
}

// per-wave redundant inclusive scan; wave0 stores cumsum; returns decay for lane's l
__device__ __forceinline__ float k1_scan(float ra, int tid, int trip,
                                         float* __restrict__ csw) {
  float v = ra;
#pragma unroll
  for (int off = 1; off < 64; off <<= 1) {
    float u = __shfl_up(v, off, 64);
    if ((tid & 63) >= off) v += u;
  }
  if (tid < 64) csw[(size_t)trip * 64 + tid] = v;
  float total = __shfl(v, 63, 64);
  return __expf(total - v);
}

__device__ __forceinline__ void k1_stage(int tid, const K1R& R, float ds,
    _Float16* Xthi, _Float16* Bthi, _Float16* Btlo) {
  const int l = tid & 63, cb2 = tid >> 6;
#pragma unroll
  for (int i = 0; i < 4; ++i) {
    float4 xv = R.rx[i], bv = R.rb[i];
    h4 hx = cvt4h(xv.x, xv.y, xv.z, xv.w);
    h4 hb, lb;
    cvt4(bv.x * ds, bv.y * ds, bv.z * ds, bv.w * ds, hb, lb);
    const int pr = cb2 * 16 + 4 * i;
    sth1(Xthi, pr + 0, l, hx.x);
    sth1(Xthi, pr + 1, l, hx.y);
    sth1(Xthi, pr + 2, l, hx.z);
    sth1(Xthi, pr + 3, l, hx.w);
    sth1(Bthi, pr + 0, l, hb.x); sth1(Btlo, pr + 0, l, lb.x);
    sth1(Bthi, pr + 1, l, hb.y); sth1(Btlo, pr + 1, l, lb.y);
    sth1(Bthi, pr + 2, l, hb.z); sth1(Btlo, pr + 2, l, lb.z);
    sth1(Bthi, pr + 3, l, hb.w); sth1(Btlo, pr + 3, l, lb.w);
  }
}

__device__ __forceinline__ void k1_mfma(int tid, int trip,
    const _Float16* Xthi, const _Float16* Bthi, const _Float16* Btlo,
    _Float16* __restrict__ states) {
  const int w = tid >> 6, li = tid & 15, g = (tid & 63) >> 4;
  f4 acc[4] = {};
#pragma unroll
  for (int ks = 0; ks < 4; ++ks) {
    const int ca = 4 * ks + g;
    h4 ahi = ldh4(Xthi, 16 * w + li, ca);
#pragma unroll
    for (int ct = 0; ct < 4; ++ct) {
      h4 bhi = ldh4(Bthi, 16 * ct + li, ca);
      h4 blo = ldh4(Btlo, 16 * ct + li, ca);
      acc[ct] = MFMA(ahi, bhi, acc[ct]);
      acc[ct] = MFMA(ahi, blo, acc[ct]);
    }
  }
  _Float16* sg = states + (size_t)trip * 4096;
#pragma unroll
  for (int r = 0; r < 4; ++r) {
    const int p = 16 * w + 4 * g + r;
#pragma unroll
    for (int ct = 0; ct < 4; ++ct)
      sg[p * 64 + 16 * ct + li] = (_Float16)acc[ct][r];
  }
}

__global__ __launch_bounds__(256) void k1_state(
    const float* __restrict__ X, const float* __restrict__ A,
    const float* __restrict__ Bm, _Float16* __restrict__ states,
    float* __restrict__ csw) {
  const int bid = blockIdx.x;
  const int h = bid & 15;
  const int cbk = (bid >> 4) & 15;
  const int b = bid >> 8;
  const int tid = threadIdx.x;
  const int c0 = cbk * 4;

  __shared__ __align__(16) _Float16 Xthi[2][4096];
  __shared__ __align__(16) _Float16 Bthi[2][4096], Btlo[2][4096];

  K1R R[2];
  k1_load(X, A, Bm, b, h, c0, tid, R[0]);
  {
    float ds = k1_scan(R[0].ra, tid, (b * NC + c0) * NH + h, csw);
    k1_stage(tid, R[0], ds, Xthi[0], Bthi[0], Btlo[0]);
  }
  k1_load(X, A, Bm, b, h, c0 + 1, tid, R[1]);

#pragma unroll
  for (int t = 0; t < 4; ++t) {
    const int sl = t & 1;
    __syncthreads();  // stage(t) visible
    k1_mfma(tid, (b * NC + c0 + t) * NH + h, Xthi[sl], Bthi[sl], Btlo[sl], states);
    if (t < 3) {
      const int so = (t + 1) & 1;
      float ds = k1_scan(R[so].ra, tid, (b * NC + c0 + t + 1) * NH + h, csw);
      k1_stage(tid, R[so], ds, Xthi[so], Bthi[so], Btlo[so]);
      if (t < 2) k1_load(X, A, Bm, b, h, c0 + t + 2, tid, R[sl]);
    }
  }
}

// ================================================================ kernel 2
// alias-free in-place scan (csw now trip-major: csw[((b*NC+c)*NH+h)*64 + l])
__global__ __launch_bounds__(256) void k2_scan(
    _Float16* __restrict__ states, const float* __restrict__ csw) {
  const int tid = threadIdx.x;
  const int sl = blockIdx.x & 15;
  const int h = (blockIdx.x >> 4) & 15;
  const int b = blockIdx.x >> 8;

  __shared__ float et[64];
  if (tid < 64)
    et[tid] = __expf(csw[(size_t)((b * NC + tid) * NH + h) * 64 + 63]);
  __syncthreads();

  const int e = sl * 256 + tid;
  const size_t base = ((size_t)b * NC * NH + h) * 4096 + e;
  const size_t zs = (size_t)NH * 4096;

  float v[64];
#pragma unroll
  for (int z = 0; z < 64; ++z) v[z] = (float)states[base + (size_t)z * zs];

  float carry = 0.f;
#pragma unroll
  for (int z = 0; z < 64; ++z) {
    const float nxt = et[z] * (carry + v[z]);
    v[z] = carry;  // entering state of chunk z
    carry = nxt;
  }

#pragma unroll
  for (int z = 0; z < 64; ++z) states[base + (size_t)z * zs] = (_Float16)v[z];
}

// ================================================================ kernel 3
struct K3R {
  float4 rc[4], rb[4], rx[4];
  h4 rg[16];       // carry fragments, ws layout [p][n] == B-frag for Yo directly
  float4 rcs;      // css[lrow], lrow = 16w+4g+{0..3}
  float rcse[4];   // exclusive cumsum at s = 16ct+li (0 if s==0)
};

__device__ __forceinline__ void k3_load(const float* X, const float* Bm,
    const float* Cm, const _Float16* states, const float* csw,
    int b, int h, int c, int tid, K3R& R) {
  const int trip = (b * NC + c) * NH + h;
  const int r0 = tid >> 2, q0 = tid & 3;
  const int l = tid & 63, pb = tid >> 6;
  const int w = tid >> 6, li = tid & 15, g = (tid & 63) >> 4;
  const float* cgp = Cm + (size_t)(b * SQ + c * 64 + r0) * 1024 + h * 64 + q0 * 16;
  const float* bgp = Bm + (size_t)(b * SQ + c * 64 + r0) * 1024 + h * 64 + q0 * 16;
  const float* xgp = X + (size_t)(b * SQ + c * 64 + l) * 1024 + h * 64 + pb * 16;
#pragma unroll
  for (int i = 0; i < 4; ++i) {
    R.rc[i] = ((const float4*)cgp)[i];
    R.rb[i] = ((const float4*)bgp)[i];
    R.rx[i] = ((const float4*)xgp)[i];
  }
  const _Float16* stg = states + (size_t)trip * 4096;
#pragma unroll
  for (int ct = 0; ct < 4; ++ct)
#pragma unroll
    for (int ks = 0; ks < 4; ++ks)
      R.rg[ct * 4 + ks] =
          *(const h4*)(stg + (16 * ct + li) * 64 + 4 * (4 * ks + g));
  const float* cw = csw + (size_t)trip * 64;
  R.rcs = *(const float4*)(cw + 16 * w + 4 * g);
#pragma unroll
  for (int ct = 0; ct < 4; ++ct) {
    const int s = 16 * ct + li;
    R.rcse[ct] = (s == 0) ? 0.f : cw[s - 1];
  }
}

__device__ __forceinline__ void k3_stage(int tid, const K3R& R,
    _Float16* Chi, _Float16* BShi, _Float16* BSlo, _Float16* XVhi) {
  const int r0 = tid >> 2, q0 = tid & 3;
  const int l = tid & 63, pb = tid >> 6;
#pragma unroll
  for (int i = 0; i < 4; ++i) {
    float4 cv = R.rc[i], bv = R.rb[i], xv = R.rx[i];
    sth4(Chi, r0, q0 * 4 + i, cvt4h(cv.x, cv.y, cv.z, cv.w));
    h4 hb, lb;
    cvt4(bv.x, bv.y, bv.z, bv.w, hb, lb);
    sth4(BShi, r0, q0 * 4 + i, hb);
    sth4(BSlo, r0, q0 * 4 + i, lb);
    h4 hx = cvt4h(xv.x, xv.y, xv.z, xv.w);
    const int pr = pb * 16 + 4 * i;
    sth1(XVhi, pr + 0, l, hx.x);
    sth1(XVhi, pr + 1, l, hx.y);
    sth1(XVhi, pr + 2, l, hx.z);
    sth1(XVhi, pr + 3, l, hx.w);
  }
}

__global__ __launch_bounds__(256) void k3_y(
    const float* __restrict__ X, const float* __restrict__ Bm,
    const float* __restrict__ Cm, const _Float16* __restrict__ states,
    const float* __restrict__ csw, float* __restrict__ Y) {
  const int bid = blockIdx.x;
  const int h = bid & 15;
  const int cbk = (bid >> 4) & 15;
  const int b = bid >> 8;
  const int tid = threadIdx.x;
  const int c0 = cbk * 4;

  __shared__ __align__(16) _Float16 Chi[2][4096];
  __shared__ __align__(16) _Float16 BShi[2][4096], BSlo[2][4096];
  __shared__ __align__(16) _Float16 XVhi[2][4096];

  const int w = tid >> 6, li = tid & 15, g = (tid & 63) >> 4;

  K3R R[2];
  k3_load(X, Bm, Cm, states, csw, b, h, c0, tid, R[0]);
  k3_stage(tid, R[0], Chi[0], BShi[0], BSlo[0], XVhi[0]);
  k3_load(X, Bm, Cm, states, csw, b, h, c0 + 1, tid, R[1]);

#pragma unroll
  for (int t = 0; t < 4; ++t) {
    const int sl = t & 1;
    const int c = c0 + t;
    __syncthreads();  // barrier 1: stage(t) visible

    // phase A+C: S[l][s] = sum_n C[l][n]B[s][n]; Yo[l][p] = sum_n C[l][n]carry[p][n]
    f4 accS[4] = {};
    f4 accC[4] = {};
#pragma unroll
    for (int ks = 0; ks < 4; ++ks) {
      const int ca = 4 * ks + g;
      h4 ahi = ldh4(Chi[sl], 16 * w + li, ca);
#pragma unroll
      for (int ct = 0; ct < 4; ++ct) {
        h4 bhi = ldh4(BShi[sl], 16 * ct + li, ca);
        h4 blo = ldh4(BSlo[sl], 16 * ct + li, ca);
        accS[ct] = MFMA(ahi, bhi, accS[ct]);
        accS[ct] = MFMA(ahi, blo, accS[ct]);
        accC[ct] = MFMA(ahi, R[sl].rg[ct * 4 + ks], accC[ct]);
      }
    }
    __syncthreads();  // barrier 2: B reads done; BShi/BSlo become SL

    // SL[l][s] = (l>=s) ? S * exp(cs[l]) * exp(-cse[s]) : 0   (split store)
    float cssv[4] = {R[sl].rcs.x, R[sl].rcs.y, R[sl].rcs.z, R[sl].rcs.w};
    float el[4];
#pragma unroll
    for (int r = 0; r < 4; ++r) el[r] = __expf(cssv[r]);
#pragma unroll
    for (int ct = 0; ct < 4; ++ct) {
      const int s = 16 * ct + li;
      const float en = __expf(-R[sl].rcse[ct]);
#pragma unroll
      for (int r = 0; r < 4; ++r) {
        const int lrow = 16 * w + 4 * g + r;
        float slv = (lrow >= s) ? accS[ct][r] * (el[r] * en) : 0.f;
        _Float16 hv = (_Float16)slv;
        _Float16 lv = (_Float16)(slv - (float)hv);
        sth1(BShi[sl], lrow, s, hv);
        sth1(BSlo[sl], lrow, s, lv);
      }
    }
    __syncthreads();  // barrier 3

    // phase B: Yd[l][p] = sum_s SL[l][s] * Xt[p][s]
    f4 accB[4] = {};
#pragma unroll
    for (int ks = 0; ks < 4; ++ks) {
      const int ca = 4 * ks + g;
      h4 ahi = ldh4(BShi[sl], 16 * w + li, ca);
      h4 alo = ldh4(BSlo[sl], 16 * w + li, ca);
#pragma unroll
      for (int ct = 0; ct < 4; ++ct) {
        h4 bhi = ldh4(XVhi[sl], 16 * ct + li, ca);
        accB[ct] = MFMA(ahi, bhi, accB[ct]);
        accB[ct] = MFMA(alo, bhi, accB[ct]);
      }
    }

    // Y = Yd + exp(cs[l]) * Yo
    float* yg = Y + (size_t)(b * SQ + c * 64) * 1024 + h * 64;
#pragma unroll
    for (int r = 0; r < 4; ++r) {
      const int lrow = 16 * w + 4 * g + r;
#pragma unroll
      for (int ct = 0; ct < 4; ++ct)
        yg[(size_t)lrow * 1024 + 16 * ct + li] = accB[ct][r] + el[r] * accC[ct][r];
    }

    if (t < 3) {
      const int so = (t + 1) & 1;
      k3_stage(tid, R[so], Chi[so], BShi[so], BSlo[so], XVhi[so]);
      if (t < 2)
        k3_load(X, Bm, Cm, states, csw, b, h, c0 + t + 2, tid, R[sl]);
    }
  }
}

// ================================================================ launch
extern "C" void kernel_launch(void* const* d_in, const int* in_sizes, int n_in,
                              void* d_out, int out_size, void* d_ws, size_t ws_size,
                              hipStream_t stream) {
  (void)in_sizes; (void)n_in; (void)out_size; (void)ws_size;
  const float* X  = (const float*)d_in[0];
  const float* A  = (const float*)d_in[1];
  const float* Bm = (const float*)d_in[2];
  const float* Cm = (const float*)d_in[3];
  float* Y = (float*)d_out;

  _Float16* states = (_Float16*)d_ws;  // 8388608 f16 = 16.8 MB
  float* csw = (float*)((char*)d_ws +
                        (size_t)NB * NC * NH * 64 * 64 * sizeof(_Float16));

  k1_state<<<NB * NH * 16, 256, 0, stream>>>(X, A, Bm, states, csw);
  k2_scan<<<NB * NH * 16, 256, 0, stream>>>(states, csw);
  k3_y<<<NB * NH * 16, 256, 0, stream>>>(X, Bm, Cm, states, csw, Y);
}